// Round 5
// baseline (73.075 us; speedup 1.0000x reference)
//
#include <hip/hip_runtime.h>
#include <hip/hip_bf16.h>

#define E 1024
#define F 12
#define R 4            // rows per region
#define RPB 16         // rows per block
#define NITER (RPB/R)  // 4 batches per block

typedef float f32x4 __attribute__((ext_vector_type(4)));

// DPP add: v += dpp(v). 0x110|N = row_shr:N (within 16-lane row), bound_ctrl=0-fill.
template<int CTRL>
__device__ __forceinline__ float dpp_add(float v) {
    int x = __builtin_amdgcn_update_dpp(0, __float_as_int(v), CTRL, 0xf, 0xf, true);
    return v + __int_as_float(x);
}
// 4-stage reduce within each 16-lane group; lane 15 (mod 16) holds the group sum.
__device__ __forceinline__ float group16_sum(float v) {
    v = dpp_add<0x111>(v);
    v = dpp_add<0x112>(v);
    v = dpp_add<0x114>(v);
    v = dpp_add<0x118>(v);
    return v;
}

// red padding: 52 floats per (buf,wave,group) slab -> 208B (16B-aligned for b128
// writes); group stride 52 % 32 = 20 banks apart -> conflict-free writer lanes.
#define RPAD 52

__global__ __launch_bounds__(256, 4) void ffq_kernel(
    const float* __restrict__ x,
    const float* __restrict__ W1,
    const float* __restrict__ b1,
    const float* __restrict__ theta,
    const float* __restrict__ W2,
    const float* __restrict__ b2,
    float* __restrict__ out,
    int nrows)
{
    const int tid   = threadIdx.x;
    const int lane  = tid & 63;
    const int wave  = tid >> 6;
    const int group = (lane >> 4) & 3;

    // ---- weights (compiler may keep or sink; cap is 128 VGPR) ----
    f32x4 w1[F];
#pragma unroll
    for (int f = 0; f < F; ++f)
        w1[f] = *reinterpret_cast<const f32x4*>(W1 + f * E + tid * 4);

    float w2l[48];                 // W2[(4t+j)][f] = w2l[12j+f]
#pragma unroll
    for (int k = 0; k < 12; ++k)
        *reinterpret_cast<f32x4*>(&w2l[4 * k]) =
            *reinterpret_cast<const f32x4*>(W2 + tid * 48 + 4 * k);

    const f32x4 bias2 = *reinterpret_cast<const f32x4*>(b2 + tid * 4);

    float b1r = 0.f, thr = 0.f;
    if (tid < 64 && (tid & 15) < F) { b1r = b1[tid & 15]; thr = theta[tid & 15]; }

    __shared__ __align__(16) float red[2][4][4][RPAD];  // [buf][wave][group][r*12+f]
    __shared__ __align__(16) float qsh[2][R][F];        // [buf][r][f]

    const int rstart = blockIdx.x * RPB;
    if (rstart >= nrows) return;

    f32x4 xv[R], xn[R];
#pragma unroll
    for (int r = 0; r < R; ++r) {
        const int row = rstart + r;
        if (row < nrows)
            xv[r] = *reinterpret_cast<const f32x4*>(x + (size_t)row * E + tid * 4);
    }

    // Region k: finisher(batch k-1) | phase1(batch k)->red[k&1] | phase2(batch k-2)
    // One barrier per region. Buffer hazards all barrier-separated:
    //   red[b]:  write ph1(k) .. read fin(k+1): bar(k). reuse ph1(k+2): bar(k+1).
    //   qsh[b]:  write fin(k) .. read ph2(k+1): bar(k). reuse fin(k+2): bar(k+1).
    for (int k = 0; k < NITER + 2; ++k) {
        const int buf = k & 1;

        // ---- finisher for batch k-1 (reads red[buf^1], writes qsh[buf^1]) ----
        if (k >= 1 && k <= NITER) {
            if (tid < 64 && (tid & 15) < F) {
                const int r = tid >> 4, fi = tid & 15;
                float s = b1r;
#pragma unroll
                for (int w = 0; w < 4; ++w)
#pragma unroll
                    for (int g = 0; g < 4; ++g)
                        s += red[buf ^ 1][w][g][r * 12 + fi];
                qsh[buf ^ 1][r][fi] = __cosf(fmaxf(s, 0.0f) + thr);
            }
        }

        // ---- phase1 for batch k (writes red[buf]) ----
        if (k < NITER) {
#pragma unroll
            for (int r = 0; r < R; ++r) {
                float part[F];
#pragma unroll
                for (int f = 0; f < F; ++f) {
                    part[f] = fmaf(xv[r].x, w1[f].x,
                              fmaf(xv[r].y, w1[f].y,
                              fmaf(xv[r].z, w1[f].z, xv[r].w * w1[f].w)));
                }
                // prefetch batch k+1 row r (consumed next region; ~full region in flight)
                if (k + 1 < NITER) {
                    const int row = rstart + (k + 1) * R + r;
                    if (row < nrows)
                        xn[r] = *reinterpret_cast<const f32x4*>(x + (size_t)row * E + tid * 4);
                }
#pragma unroll
                for (int f = 0; f < F; ++f) part[f] = group16_sum(part[f]);

                if ((lane & 15) == 15) {
#pragma unroll
                    for (int fq = 0; fq < 3; ++fq) {
                        f32x4 v = { part[4*fq], part[4*fq+1], part[4*fq+2], part[4*fq+3] };
                        *reinterpret_cast<f32x4*>(&red[buf][wave][group][r * 12 + 4 * fq]) = v;
                    }
                }
            }
        }

        // ---- phase2 for batch k-2 (reads qsh[buf], nontemporal store) ----
        if (k >= 2) {
            const int bi = k - 2;
#pragma unroll
            for (int r = 0; r < R; ++r) {
                const int row = rstart + bi * R + r;
                if (row < nrows) {
                    float qf[F];
                    *reinterpret_cast<f32x4*>(&qf[0]) = *reinterpret_cast<const f32x4*>(&qsh[buf][r][0]);
                    *reinterpret_cast<f32x4*>(&qf[4]) = *reinterpret_cast<const f32x4*>(&qsh[buf][r][4]);
                    *reinterpret_cast<f32x4*>(&qf[8]) = *reinterpret_cast<const f32x4*>(&qsh[buf][r][8]);

                    f32x4 o;
#pragma unroll
                    for (int j = 0; j < 4; ++j) {
                        float acc = bias2[j];
#pragma unroll
                        for (int f = 0; f < F; ++f) acc = fmaf(qf[f], w2l[12 * j + f], acc);
                        o[j] = acc;
                    }
                    __builtin_nontemporal_store(o,
                        reinterpret_cast<f32x4*>(out + (size_t)row * E + tid * 4));
                }
            }
        }

        if (k + 1 < NITER) {
#pragma unroll
            for (int r = 0; r < R; ++r) xv[r] = xn[r];
        }
        if (k + 1 < NITER + 2) __syncthreads();
    }
}

extern "C" void kernel_launch(void* const* d_in, const int* in_sizes, int n_in,
                              void* d_out, int out_size, void* d_ws, size_t ws_size,
                              hipStream_t stream)
{
    const float* x     = (const float*)d_in[0];
    const float* W1    = (const float*)d_in[1];
    const float* b1    = (const float*)d_in[2];
    const float* theta = (const float*)d_in[3];
    const float* W2    = (const float*)d_in[4];
    const float* b2    = (const float*)d_in[5];
    float* out = (float*)d_out;

    const int nrows = in_sizes[0] / E;            // B*S = 16384
    const int grid  = (nrows + RPB - 1) / RPB;    // 1024 blocks

    ffq_kernel<<<grid, 256, 0, stream>>>(x, W1, b1, theta, W2, b2, out, nrows);
}

// Round 6
// 38.608 us; speedup vs baseline: 1.8927x; 1.8927x over previous
//
#include <hip/hip_runtime.h>
#include <hip/hip_bf16.h>

#define E 1024
#define F 12
#define R 4            // rows per batch
#define RPB 16         // rows per block
#define NB (RPB / R)   // 4 batches

typedef float f32x4 __attribute__((ext_vector_type(4)));

// DPP add: v += dpp(v). 0x110|N = row_shr:N within 16-lane row, bound_ctrl 0-fill.
template<int CTRL>
__device__ __forceinline__ float dpp_add(float v) {
    int x = __builtin_amdgcn_update_dpp(0, __float_as_int(v), CTRL, 0xf, 0xf, true);
    return v + __int_as_float(x);
}
// 4-stage reduce within each 16-lane group; lane 15 (mod 16) holds the group sum.
__device__ __forceinline__ float group16_sum(float v) {
    v = dpp_add<0x111>(v);
    v = dpp_add<0x112>(v);
    v = dpp_add<0x114>(v);
    v = dpp_add<0x118>(v);
    return v;
}

__global__ __launch_bounds__(256, 2) void ffq_kernel(
    const float* __restrict__ x,
    const float* __restrict__ W1,
    const float* __restrict__ b1,
    const float* __restrict__ theta,
    const float* __restrict__ W2,
    const float* __restrict__ b2,
    float* __restrict__ out,
    int nrows)
{
    const int tid  = threadIdx.x;
    const int lane = tid & 63;
    const int wave = tid >> 6;
    const int grp  = lane >> 4;   // 16-lane group / finisher row index
    const int fi   = lane & 15;   // finisher f index (active if < 12)

    // ---- register-resident weights ----
    f32x4 w1[F];                  // W1[f][4t..4t+3]
#pragma unroll
    for (int f = 0; f < F; ++f)
        w1[f] = *reinterpret_cast<const f32x4*>(W1 + f * E + tid * 4);

    float w2l[48];                // W2[(4t+j)][f] = w2l[12j+f]
#pragma unroll
    for (int k = 0; k < 12; ++k)
        *reinterpret_cast<f32x4*>(&w2l[4 * k]) =
            *reinterpret_cast<const f32x4*>(W2 + tid * 48 + 4 * k);

    const f32x4 bias2 = *reinterpret_cast<const f32x4*>(b2 + tid * 4);

    // finisher constants needed by EVERY wave now
    float b1r = 0.f, thr = 0.f;
    if (fi < F) { b1r = b1[fi]; thr = theta[fi]; }

    // red[buf][wave][grp][r][f] (f padded to 16 for aligned f32x4 writes): 8 KB
    __shared__ __align__(16) float red[2][4][4][R][16];
    // wave-private q slabs -> no barrier between finisher write and phase2 read
    __shared__ __align__(16) float qsh[4][R][16];

    const int rstart = blockIdx.x * RPB;
    if (rstart >= nrows) return;          // uniform per block; barriers below safe

    f32x4 xv[R];
#pragma unroll
    for (int r = 0; r < R; ++r)
        if (rstart + r < nrows)
            xv[r] = *reinterpret_cast<const f32x4*>(x + (size_t)(rstart + r) * E + tid * 4);

    // Hazards (one barrier per batch, at *):
    //   red[b]: write ph1(k) .. read fin(k) sep by bar(k)*; rewrite ph1(k+2)
    //           after bar(k+1), fin(k) reads precede bar(k+1) in program order.
    //   qsh[w]: wave-private; write fin(k) -> read ph2(k) -> rewrite fin(k+1)
    //           all same-wave LDS program order.
    for (int k = 0; k < NB; ++k) {
        const int buf = k & 1;

        // ---- phase1: partial dots + 4-stage DPP group reduce ----
#pragma unroll
        for (int r = 0; r < R; ++r) {
            float part[F];
#pragma unroll
            for (int f = 0; f < F; ++f) {
                part[f] = fmaf(xv[r].x, w1[f].x,
                          fmaf(xv[r].y, w1[f].y,
                          fmaf(xv[r].z, w1[f].z, xv[r].w * w1[f].w)));
            }
#pragma unroll
            for (int f = 0; f < F; ++f) part[f] = group16_sum(part[f]);

            if (fi == 15) {   // one writer lane per 16-lane group
#pragma unroll
                for (int q = 0; q < 3; ++q) {
                    f32x4 v = { part[4*q], part[4*q+1], part[4*q+2], part[4*q+3] };
                    *reinterpret_cast<f32x4*>(&red[buf][wave][grp][r][4 * q]) = v;
                }
            }
        }

        __syncthreads();   // (*) the only barrier per batch

        // ---- prefetch next batch straight into xv (xv dead after phase1);
        //      in flight across finisher + phase2 + loop-back ----
        if (k + 1 < NB) {
#pragma unroll
            for (int r = 0; r < R; ++r) {
                const int row = rstart + (k + 1) * R + r;
                if (row < nrows)
                    xv[r] = *reinterpret_cast<const f32x4*>(x + (size_t)row * E + tid * 4);
            }
        }

        // ---- redundant per-wave finisher: 48 lanes compute ALL 48 q's ----
        if (fi < F) {
            float s = b1r;
#pragma unroll
            for (int w = 0; w < 4; ++w)
#pragma unroll
                for (int g = 0; g < 4; ++g)
                    s += red[buf][w][g][grp][fi];
            qsh[wave][grp][fi] = __cosf(fmaxf(s, 0.0f) + thr);
        }

        // ---- phase2: reads own wave's qsh (same-wave order, no barrier) ----
#pragma unroll
        for (int r = 0; r < R; ++r) {
            const int row = rstart + k * R + r;
            if (row < nrows) {
                float qf[F];
                *reinterpret_cast<f32x4*>(&qf[0]) = *reinterpret_cast<const f32x4*>(&qsh[wave][r][0]);
                *reinterpret_cast<f32x4*>(&qf[4]) = *reinterpret_cast<const f32x4*>(&qsh[wave][r][4]);
                *reinterpret_cast<f32x4*>(&qf[8]) = *reinterpret_cast<const f32x4*>(&qsh[wave][r][8]);

                f32x4 o;
#pragma unroll
                for (int j = 0; j < 4; ++j) {
                    float acc = bias2[j];
#pragma unroll
                    for (int f = 0; f < F; ++f) acc = fmaf(qf[f], w2l[12 * j + f], acc);
                    o[j] = acc;
                }
                __builtin_nontemporal_store(o,
                    reinterpret_cast<f32x4*>(out + (size_t)row * E + tid * 4));
            }
        }
    }
}

extern "C" void kernel_launch(void* const* d_in, const int* in_sizes, int n_in,
                              void* d_out, int out_size, void* d_ws, size_t ws_size,
                              hipStream_t stream)
{
    const float* x     = (const float*)d_in[0];
    const float* W1    = (const float*)d_in[1];
    const float* b1    = (const float*)d_in[2];
    const float* theta = (const float*)d_in[3];
    const float* W2    = (const float*)d_in[4];
    const float* b2    = (const float*)d_in[5];
    float* out = (float*)d_out;

    const int nrows = in_sizes[0] / E;            // B*S = 16384
    const int grid  = (nrows + RPB - 1) / RPB;    // 1024 blocks

    ffq_kernel<<<grid, 256, 0, stream>>>(x, W1, b1, theta, W2, b2, out, nrows);
}